// Round 6
// baseline (619.892 us; speedup 1.0000x reference)
//
#include <hip/hip_runtime.h>

#define NN 100000
#define NE 1600000
#define NB_SCAN 391   // ceil(NN/256)
#define NBUCK 1563    // ceil(NN/64)
#define NBG 1563      // ceil(NN/64) rows/64 for fused GEMM
#define NBXB 12500    // NN*32/256 blocks for x->bf16
#define NBDEG 6250    // NE/256

// ws layout (bytes):
//   deg:  0         dinv: 400000      row_start: 800000 ((NN+1)*4)
//   bcur: 1200016 (NBUCK*4)           part: 1206272
//   xb:   1216000 (25.6 MB)           ebuf: 26816000 (12.8 MB, int2{src,dst})
//   csr:  39616000 (12.8 MB, int2{src,w})   P: 52416000 (NN*256 = 25.6 MB)
// total 78.0 MB.  P slot (256 B): agg_x bf16 [0,256) -> gemm12 overwrites
// [0,128) with t2 bf16 -> agg2 gathers [0,128).

typedef short bf16x8 __attribute__((ext_vector_type(8)));
typedef float f32x4  __attribute__((ext_vector_type(4)));

__device__ __forceinline__ float b2f(unsigned short u) {
    return __uint_as_float(((unsigned int)u) << 16);
}
__device__ __forceinline__ unsigned short f2b(float f) {
    unsigned int x = __float_as_uint(f);
    x += 0x7FFFu + ((x >> 16) & 1u);   // RNE
    return (unsigned short)(x >> 16);
}

// ---- fused: x->bf16 (blocks [0,NBXB)) + degree count (blocks [NBXB,..)) ----
__global__ __launch_bounds__(256) void k_xb_deg(const float* __restrict__ x,
                                                unsigned short* __restrict__ xb,
                                                const int* __restrict__ dst,
                                                int* __restrict__ deg) {
    int b = blockIdx.x;
    if (b < NBXB) {
        int id = b * 256 + threadIdx.x;
        float4 v = ((const float4*)x)[id];
        ushort4 o;
        o.x = f2b(v.x); o.y = f2b(v.y); o.z = f2b(v.z); o.w = f2b(v.w);
        ((ushort4*)xb)[id] = o;
    } else {
        int e = (b - NBXB) * 256 + threadIdx.x;
        unsigned d = (unsigned)dst[e];
        if (d < NN) atomicAdd(&deg[d], 1);
    }
}

// ---- block scan of deg + dinv ----
__global__ __launch_bounds__(256) void k_scan1(const int* __restrict__ deg,
                                               int* __restrict__ row_start,
                                               int* __restrict__ part,
                                               float* __restrict__ dinv) {
    __shared__ int s[256];
    int tid = threadIdx.x;
    int i = blockIdx.x * 256 + tid;
    int v = (i < NN) ? deg[i] : 0;
    if (i < NN) dinv[i] = rsqrtf(fmaxf((float)v + 1.0f, 1.0f));
    s[tid] = v;
    __syncthreads();
    for (int off = 1; off < 256; off <<= 1) {
        int t = (tid >= off) ? s[tid - off] : 0;
        __syncthreads();
        s[tid] += t;
        __syncthreads();
    }
    if (i < NN) row_start[i] = s[tid] - v;
    if (tid == 255) part[blockIdx.x] = s[255];
}

__global__ __launch_bounds__(512) void k_scan2(int* __restrict__ part) {
    __shared__ int s[512];
    int tid = threadIdx.x;
    int v = (tid < NB_SCAN) ? part[tid] : 0;
    s[tid] = v;
    __syncthreads();
    for (int off = 1; off < 512; off <<= 1) {
        int t = (tid >= off) ? s[tid - off] : 0;
        __syncthreads();
        s[tid] += t;
        __syncthreads();
    }
    if (tid < NB_SCAN) part[tid] = s[tid] - v;
}

// ---- finalize row_start; init per-bucket cursors ----
__global__ __launch_bounds__(256) void k_scan3(int* __restrict__ row_start,
                                               const int* __restrict__ part,
                                               int* __restrict__ bcur) {
    int i = blockIdx.x * 256 + threadIdx.x;
    if (i < NN) {
        int rs = row_start[i] + part[blockIdx.x];
        row_start[i] = rs;
        if ((i & 63) == 0) bcur[i >> 6] = rs;
    }
    if (i == 0) row_start[NN] = NE;
}

// ---- pass B: scatter edges to bucket-sorted order (1563 write frontiers) ----
__global__ __launch_bounds__(256) void k_binB(const int* __restrict__ src,
                                              const int* __restrict__ dst,
                                              int* __restrict__ bcur,
                                              int2* __restrict__ ebuf) {
    int e = blockIdx.x * 256 + threadIdx.x;
    if (e >= NE) return;
    unsigned s = (unsigned)src[e], d = (unsigned)dst[e];
    if (s >= NN || d >= NN) return;
    int pos = atomicAdd(&bcur[d >> 6], 1);
    ebuf[pos] = make_int2((int)s, (int)d);
}

// ---- pass C: exact placement within bucket via LDS cursors ----
__global__ __launch_bounds__(256) void k_binC(const int* __restrict__ row_start,
                                              const float* __restrict__ dinv,
                                              const int2* __restrict__ ebuf,
                                              int2* __restrict__ csr) {
    __shared__ int cur[64];
    __shared__ float dv[64];
    int b = blockIdx.x, tid = threadIdx.x;
    int n0 = b * 64;
    if (tid < 64) {
        int node = n0 + tid;
        cur[tid] = (node < NN) ? row_start[node] : 0;
        dv[tid]  = (node < NN) ? dinv[node] : 0.f;
    }
    __syncthreads();
    int base = row_start[n0];
    int endn = n0 + 64; if (endn > NN) endn = NN;
    int end  = row_start[endn];
    for (int i = base + tid; i < end; i += 256) {
        int2 rec = ebuf[i];
        int dl = rec.y - n0;
        int pos = atomicAdd(&cur[dl], 1);
        float w = dinv[rec.x] * dv[dl];
        csr[pos] = make_int2(rec.x, __float_as_int(w));
    }
}

// ---- layer-1 aggregate: P[n] = bf16( xb[n]*sn + sum w_e*xb[src_e] ) ----
__global__ __launch_bounds__(256) void k_agg1(const unsigned short* __restrict__ xb,
                                              const float* __restrict__ dinv,
                                              const int* __restrict__ row_start,
                                              const int2* __restrict__ csr,
                                              char* __restrict__ P) {
    int node = blockIdx.x * 4 + (threadIdx.x >> 6);   // grid = NN/4 exactly
    int lane = threadIdx.x & 63;
    float dv = dinv[node]; float sn = dv * dv;
    unsigned int sv = ((const unsigned int*)(xb + (size_t)node * 128))[lane];
    float ax = b2f((unsigned short)(sv & 0xFFFF)) * sn;
    float ay = b2f((unsigned short)(sv >> 16)) * sn;
    int base = row_start[node], end = row_start[node + 1];
    for (int i0 = base; i0 < end; i0 += 64) {
        int idx = i0 + lane;
        int2 rec = make_int2(0, 0);
        if (idx < end) rec = csr[idx];
        int m = min(64, end - i0);
        int j = 0;
        for (; j + 1 < m; j += 2) {
            int   s0 = __shfl(rec.x, j),  s1 = __shfl(rec.x, j + 1);
            float w0 = __int_as_float(__shfl(rec.y, j));
            float w1 = __int_as_float(__shfl(rec.y, j + 1));
            unsigned int v0 = ((const unsigned int*)(xb + (size_t)s0 * 128))[lane];
            unsigned int v1 = ((const unsigned int*)(xb + (size_t)s1 * 128))[lane];
            ax = fmaf(b2f((unsigned short)(v0 & 0xFFFF)), w0, ax);
            ay = fmaf(b2f((unsigned short)(v0 >> 16)),    w0, ay);
            ax = fmaf(b2f((unsigned short)(v1 & 0xFFFF)), w1, ax);
            ay = fmaf(b2f((unsigned short)(v1 >> 16)),    w1, ay);
        }
        if (j < m) {
            int s0 = __shfl(rec.x, j);
            float w0 = __int_as_float(__shfl(rec.y, j));
            unsigned int v0 = ((const unsigned int*)(xb + (size_t)s0 * 128))[lane];
            ax = fmaf(b2f((unsigned short)(v0 & 0xFFFF)), w0, ax);
            ay = fmaf(b2f((unsigned short)(v0 >> 16)),    w0, ay);
        }
    }
    unsigned int o = (unsigned int)f2b(ax) | ((unsigned int)f2b(ay) << 16);
    ((unsigned int*)(P + (size_t)node * 256))[lane] = o;
}

// ---- fused GEMM1+GEMM2 (MFMA): t2 = bf16( relu(agg@W1+b1) @ W2 ), in-place ----
// h2 lives only in LDS (C-layout -> A-layout round trip). 64 rows/block.
__global__ __launch_bounds__(256) void k_gemm12(const float* __restrict__ W1,
                                                const float* __restrict__ b1,
                                                const float* __restrict__ W2,
                                                char* __restrict__ P) {
    __shared__ short Wl1[16384];                    // 32 KB  [ct8][ks4][lane64][j8]
    __shared__ short Wl2[8192];                     // 16 KB  [ct4][ks4][lane64][j8]
    __shared__ __align__(16) short Cl[4][16][128];  // 16 KB h2 staging / t2 reuse
    const int tid = threadIdx.x;
    const int w = tid >> 6, lane = tid & 63;
    const int r0 = blockIdx.x * 64;

    for (int i = tid; i < 16384; i += 256) {
        int j = i & 7, l = (i >> 3) & 63, ks = (i >> 9) & 3, ct = i >> 11;
        int k = ks * 32 + ((l >> 4) << 3) + j;
        int c = ct * 16 + (l & 15);
        Wl1[i] = (short)f2b(W1[k * 128 + c]);
    }
    for (int i = tid; i < 8192; i += 256) {
        int j = i & 7, l = (i >> 3) & 63, ks = (i >> 9) & 3, ct = i >> 11;
        int k = ks * 32 + ((l >> 4) << 3) + j;
        int c = ct * 16 + (l & 15);
        Wl2[i] = (short)f2b(W2[k * 64 + c]);
    }
    __syncthreads();

    const int m = r0 + w * 16 + (lane & 15);
    const int quad = lane >> 4;
    const bool mok = (m < NN);
    bf16x8 a[4];
#pragma unroll
    for (int ks = 0; ks < 4; ++ks) {
        if (mok) a[ks] = *(const bf16x8*)(P + (size_t)m * 256 + (ks * 32 + quad * 8) * 2);
        else     a[ks] = bf16x8{0,0,0,0,0,0,0,0};
    }
    // layer 1: 8 col-tiles of 16
#pragma unroll
    for (int ct = 0; ct < 8; ++ct) {
        f32x4 c = {0.f, 0.f, 0.f, 0.f};
#pragma unroll
        for (int ks = 0; ks < 4; ++ks) {
            bf16x8 b = *(const bf16x8*)&Wl1[((ct * 4 + ks) * 64 + lane) * 8];
            c = __builtin_amdgcn_mfma_f32_16x16x32_bf16(a[ks], b, c, 0, 0, 0);
        }
        int col = ct * 16 + (lane & 15);
        float bias = b1[col];
#pragma unroll
        for (int r = 0; r < 4; ++r)
            Cl[w][quad * 4 + r][col] = (short)f2b(fmaxf(c[r] + bias, 0.f));
    }
    __syncthreads();
    // h2 C-layout -> A-layout
    bf16x8 a2[4];
#pragma unroll
    for (int ks = 0; ks < 4; ++ks)
        a2[ks] = *(const bf16x8*)&Cl[w][lane & 15][ks * 32 + quad * 8];
    __syncthreads();
    // layer 2: 4 col-tiles of 16, stage t2 into reused Cl space
    short* Ct = &Cl[0][0][0];   // [64 rows][64 cols]
#pragma unroll
    for (int ct = 0; ct < 4; ++ct) {
        f32x4 c = {0.f, 0.f, 0.f, 0.f};
#pragma unroll
        for (int ks = 0; ks < 4; ++ks) {
            bf16x8 b = *(const bf16x8*)&Wl2[((ct * 4 + ks) * 64 + lane) * 8];
            c = __builtin_amdgcn_mfma_f32_16x16x32_bf16(a2[ks], b, c, 0, 0, 0);
        }
        int col = ct * 16 + (lane & 15);
#pragma unroll
        for (int r = 0; r < 4; ++r)
            Ct[(w * 16 + quad * 4 + r) * 64 + col] = (short)f2b(c[r]);
    }
    __syncthreads();
    // write t2 (16 rows x 128 B per wave): 2 rows per iter, 32 lanes each
    for (int it = 0; it < 8; ++it) {
        int row = it * 2 + (lane >> 5), u = lane & 31;
        int node = r0 + w * 16 + row;
        if (node < NN)
            *(unsigned int*)(P + (size_t)node * 256 + u * 4) =
                ((const unsigned int*)&Ct[(w * 16 + row) * 64])[u];
    }
}

// ---- layer-2 aggregate + epilogue: out = t2*sn + sum w_e*t2[src] + b2 ----
__global__ __launch_bounds__(256) void k_agg2(const float* __restrict__ dinv,
                                              const int* __restrict__ row_start,
                                              const int2* __restrict__ csr,
                                              const char* __restrict__ P,
                                              const float* __restrict__ b2,
                                              float* __restrict__ outp) {
    int node = blockIdx.x * 4 + (threadIdx.x >> 6);   // grid = NN/4 exactly
    int lane = threadIdx.x & 63;
    float dv = dinv[node]; float sn = dv * dv;
    float acc = b2f(*(const unsigned short*)(P + (size_t)node * 256 + lane * 2)) * sn;
    int base = row_start[node], end = row_start[node + 1];
    for (int i0 = base; i0 < end; i0 += 64) {
        int idx = i0 + lane;
        int2 rec = make_int2(0, 0);
        if (idx < end) rec = csr[idx];
        int m = min(64, end - i0);
        int j = 0;
        for (; j + 1 < m; j += 2) {
            int   s0 = __shfl(rec.x, j),  s1 = __shfl(rec.x, j + 1);
            float w0 = __int_as_float(__shfl(rec.y, j));
            float w1 = __int_as_float(__shfl(rec.y, j + 1));
            float v0 = b2f(*(const unsigned short*)(P + (size_t)s0 * 256 + lane * 2));
            float v1 = b2f(*(const unsigned short*)(P + (size_t)s1 * 256 + lane * 2));
            acc = fmaf(v0, w0, acc);
            acc = fmaf(v1, w1, acc);
        }
        if (j < m) {
            int s0 = __shfl(rec.x, j);
            float w0 = __int_as_float(__shfl(rec.y, j));
            float v0 = b2f(*(const unsigned short*)(P + (size_t)s0 * 256 + lane * 2));
            acc = fmaf(v0, w0, acc);
        }
    }
    outp[(size_t)node * 64 + lane] = acc + b2[lane];
}

extern "C" void kernel_launch(void* const* d_in, const int* in_sizes, int n_in,
                              void* d_out, int out_size, void* d_ws, size_t ws_size,
                              hipStream_t stream) {
    const float* x  = (const float*)d_in[0];
    const int*   ei = (const int*)d_in[1];
    const float* W1 = (const float*)d_in[2];
    const float* b1 = (const float*)d_in[3];
    const float* W2 = (const float*)d_in[4];
    const float* b2 = (const float*)d_in[5];
    float* out = (float*)d_out;
    const int* src = ei;
    const int* dst = ei + NE;

    char* ws = (char*)d_ws;
    int*            deg       = (int*)(ws + 0);
    float*          dinv      = (float*)(ws + 400000);
    int*            row_start = (int*)(ws + 800000);
    int*            bcur      = (int*)(ws + 1200016);
    int*            part      = (int*)(ws + 1206272);
    unsigned short* xb        = (unsigned short*)(ws + 1216000);
    int2*           ebuf      = (int2*)(ws + 26816000);
    int2*           csr       = (int2*)(ws + 39616000);
    char*           P         = ws + 52416000;

    hipMemsetAsync(deg, 0, (size_t)NN * 4, stream);

    k_xb_deg<<<NBXB + NBDEG, 256, 0, stream>>>(x, xb, dst, deg);
    k_scan1 <<<NB_SCAN, 256, 0, stream>>>(deg, row_start, part, dinv);
    k_scan2 <<<1, 512, 0, stream>>>(part);
    k_scan3 <<<NB_SCAN, 256, 0, stream>>>(row_start, part, bcur);
    k_binB  <<<NBDEG, 256, 0, stream>>>(src, dst, bcur, ebuf);
    k_binC  <<<NBUCK, 256, 0, stream>>>(row_start, dinv, ebuf, csr);

    k_agg1  <<<NN / 4, 256, 0, stream>>>(xb, dinv, row_start, csr, P);
    k_gemm12<<<NBG, 256, 0, stream>>>(W1, b1, W2, P);
    k_agg2  <<<NN / 4, 256, 0, stream>>>(dinv, row_start, csr, P, b2, out);
}

// Round 7
// 374.128 us; speedup vs baseline: 1.6569x; 1.6569x over previous
//
#include <hip/hip_runtime.h>

#define NN 100000
#define NE 1600000
#define NBUCK 1563     // ceil(NN/64)
#define NBH 128        // histogram/placement blocks
#define CHUNK 12500    // NE/NBH
#define NBXB 12500     // NN*32/256 blocks for x->bf16
#define NBG 1563       // ceil(NN/64) for fused GEMM

// ws layout (bytes):
//   xb:    0           (25,600,000)  bf16 x
//   ghist: 25,600,000  (800,256)     [block i][bucket k] row-major
//   boffT: 26,400,768  (800,256)     [bucket k][block i] col-major
//   tot:   27,201,536  (6,252)       per-bucket totals
//   bbase: 27,208,192  (6,252)       per-bucket base (exclusive scan of tot)
//   row_start: 27,214,848 ((NN+1)*4)
//   dinv:  27,614,976  (400,000)
//   ebuf:  28,014,976  (6,400,000)   bucket-sorted packed {src|dstlo<<17}
//   csr:   34,414,976  (6,400,000)   node-sorted src-only
//   P:     40,814,976  (25,600,000)  per-node 256B slot: agg_x bf16 -> t2 bf16 [0,128)
// total 66.4 MB. No memsets needed.

typedef short bf16x8 __attribute__((ext_vector_type(8)));
typedef float f32x4  __attribute__((ext_vector_type(4)));

__device__ __forceinline__ float b2f(unsigned short u) {
    return __uint_as_float(((unsigned int)u) << 16);
}
__device__ __forceinline__ unsigned short f2b(float f) {
    unsigned int x = __float_as_uint(f);
    x += 0x7FFFu + ((x >> 16) & 1u);   // RNE
    return (unsigned short)(x >> 16);
}

// ---- fused: x->bf16 (blocks [0,NBXB)) + bucket histogram (blocks [NBXB,NBXB+NBH)) ----
__global__ __launch_bounds__(256) void k_pre(const float* __restrict__ x,
                                             unsigned short* __restrict__ xb,
                                             const int* __restrict__ dst,
                                             int* __restrict__ ghist) {
    int b = blockIdx.x;
    if (b < NBXB) {
        int id = b * 256 + threadIdx.x;
        float4 v = ((const float4*)x)[id];
        ushort4 o;
        o.x = f2b(v.x); o.y = f2b(v.y); o.z = f2b(v.z); o.w = f2b(v.w);
        ((ushort4*)xb)[id] = o;
        return;
    }
    __shared__ int h[NBUCK];
    int tid = threadIdx.x;
    int i = b - NBXB;
    for (int k = tid; k < NBUCK; k += 256) h[k] = 0;
    __syncthreads();
    int e0 = i * CHUNK;
    for (int e = e0 + tid; e < e0 + CHUNK; e += 256) {
        unsigned d = (unsigned)dst[e];
        if (d < NN) atomicAdd(&h[d >> 6], 1);
    }
    __syncthreads();
    for (int k = tid; k < NBUCK; k += 256) ghist[i * NBUCK + k] = h[k];
}

// ---- per-bucket scan over blocks: boffT[k][i], tot[k] ----
__global__ __launch_bounds__(256) void k_scanB(const int* __restrict__ ghist,
                                               int* __restrict__ boffT,
                                               int* __restrict__ tot) {
    int k = blockIdx.x * 256 + threadIdx.x;
    if (k >= NBUCK) return;
    int sum = 0;
#pragma unroll 8
    for (int i = 0; i < NBH; ++i) {
        int c = ghist[i * NBUCK + k];
        boffT[k * NBH + i] = sum;
        sum += c;
    }
    tot[k] = sum;
}

// ---- exclusive scan of bucket totals -> bbase ----
__global__ __launch_bounds__(256) void k_scanT(const int* __restrict__ tot,
                                               int* __restrict__ bbase) {
    __shared__ int s[256];
    int tid = threadIdx.x;
    int k0 = tid * 7;
    int v[7]; int S = 0;
#pragma unroll
    for (int q = 0; q < 7; ++q) {
        int k = k0 + q;
        v[q] = (k < NBUCK) ? tot[k] : 0;
        S += v[q];
    }
    s[tid] = S;
    __syncthreads();
    for (int off = 1; off < 256; off <<= 1) {
        int t = (tid >= off) ? s[tid - off] : 0;
        __syncthreads();
        s[tid] += t;
        __syncthreads();
    }
    int run = s[tid] - S;   // exclusive
#pragma unroll
    for (int q = 0; q < 7; ++q) {
        int k = k0 + q;
        if (k < NBUCK) { bbase[k] = run; run += v[q]; }
    }
}

// ---- placement: bucket-sorted packed records via LDS cursors (no global atomics) ----
__global__ __launch_bounds__(256) void k_place(const int* __restrict__ src,
                                               const int* __restrict__ dst,
                                               const int* __restrict__ bbase,
                                               const int* __restrict__ boffT,
                                               int* __restrict__ ebuf) {
    __shared__ int cur[NBUCK];
    int tid = threadIdx.x, i = blockIdx.x;
    for (int k = tid; k < NBUCK; k += 256) cur[k] = bbase[k] + boffT[k * NBH + i];
    __syncthreads();
    int e0 = i * CHUNK;
    for (int e = e0 + tid; e < e0 + CHUNK; e += 256) {
        unsigned d = (unsigned)dst[e];
        if (d >= NN) continue;
        unsigned s = (unsigned)src[e];
        if (s >= NN) s = 0;
        int pos = atomicAdd(&cur[d >> 6], 1);
        ebuf[pos] = (int)(s | ((d & 63u) << 17));
    }
}

// ---- per-bucket: count per node, write row_start/dinv, place src-only csr ----
__global__ __launch_bounds__(256) void k_binC(const int* __restrict__ bbase,
                                              const int* __restrict__ tot,
                                              const int* __restrict__ ebuf,
                                              int* __restrict__ row_start,
                                              float* __restrict__ dinv,
                                              int* __restrict__ csr) {
    __shared__ int cnt[64], excl[64], cur[64];
    int b = blockIdx.x, tid = threadIdx.x;
    int n0 = b * 64;
    int base = bbase[b], end = base + tot[b];
    if (tid < 64) cnt[tid] = 0;
    __syncthreads();
    for (int i = base + tid; i < end; i += 256)
        atomicAdd(&cnt[((unsigned)ebuf[i]) >> 17], 1);
    __syncthreads();
    if (tid == 0) {
        int run = 0;
        for (int t = 0; t < 64; ++t) { excl[t] = run; run += cnt[t]; }
    }
    __syncthreads();
    if (tid < 64) {
        int node = n0 + tid;
        if (node < NN) {
            row_start[node] = base + excl[tid];
            dinv[node] = rsqrtf((float)cnt[tid] + 1.0f);
        }
        cur[tid] = base + excl[tid];
    }
    if (b == NBUCK - 1 && tid == 0) row_start[NN] = end;
    __syncthreads();
    for (int i = base + tid; i < end; i += 256) {
        unsigned rec = (unsigned)ebuf[i];
        int pos = atomicAdd(&cur[rec >> 17], 1);
        csr[pos] = (int)(rec & 0x1FFFFu);
    }
}

// ---- layer-1 aggregate: P[n] = bf16( xb[n]*sn + sum w_e*xb[src_e] ), MLP=4 ----
__global__ __launch_bounds__(256) void k_agg1(const unsigned short* __restrict__ xb,
                                              const float* __restrict__ dinv,
                                              const int* __restrict__ row_start,
                                              const int* __restrict__ csr,
                                              char* __restrict__ P) {
    int node = blockIdx.x * 4 + (threadIdx.x >> 6);   // grid = NN/4 exactly
    int lane = threadIdx.x & 63;
    float dv = dinv[node]; float sn = dv * dv;
    unsigned int sv = ((const unsigned int*)(xb + (size_t)node * 128))[lane];
    float ax = b2f((unsigned short)(sv & 0xFFFF)) * sn;
    float ay = b2f((unsigned short)(sv >> 16)) * sn;
    int base = row_start[node], end = row_start[node + 1];
    for (int i0 = base; i0 < end; i0 += 64) {
        int idx = i0 + lane;
        int s = (idx < end) ? csr[idx] : 0;
        float wv = (idx < end) ? dinv[s] * dv : 0.f;
        int m = min(64, end - i0);
        int j = 0;
        for (; j + 3 < m; j += 4) {
            int   s0 = __shfl(s, j),  s1 = __shfl(s, j + 1);
            int   s2 = __shfl(s, j + 2), s3 = __shfl(s, j + 3);
            float w0 = __shfl(wv, j), w1 = __shfl(wv, j + 1);
            float w2 = __shfl(wv, j + 2), w3 = __shfl(wv, j + 3);
            unsigned int v0 = ((const unsigned int*)(xb + (size_t)s0 * 128))[lane];
            unsigned int v1 = ((const unsigned int*)(xb + (size_t)s1 * 128))[lane];
            unsigned int v2 = ((const unsigned int*)(xb + (size_t)s2 * 128))[lane];
            unsigned int v3 = ((const unsigned int*)(xb + (size_t)s3 * 128))[lane];
            ax = fmaf(b2f((unsigned short)(v0 & 0xFFFF)), w0, ax);
            ay = fmaf(b2f((unsigned short)(v0 >> 16)),    w0, ay);
            ax = fmaf(b2f((unsigned short)(v1 & 0xFFFF)), w1, ax);
            ay = fmaf(b2f((unsigned short)(v1 >> 16)),    w1, ay);
            ax = fmaf(b2f((unsigned short)(v2 & 0xFFFF)), w2, ax);
            ay = fmaf(b2f((unsigned short)(v2 >> 16)),    w2, ay);
            ax = fmaf(b2f((unsigned short)(v3 & 0xFFFF)), w3, ax);
            ay = fmaf(b2f((unsigned short)(v3 >> 16)),    w3, ay);
        }
        for (; j < m; ++j) {
            int s0 = __shfl(s, j);
            float w0 = __shfl(wv, j);
            unsigned int v0 = ((const unsigned int*)(xb + (size_t)s0 * 128))[lane];
            ax = fmaf(b2f((unsigned short)(v0 & 0xFFFF)), w0, ax);
            ay = fmaf(b2f((unsigned short)(v0 >> 16)),    w0, ay);
        }
    }
    unsigned int o = (unsigned int)f2b(ax) | ((unsigned int)f2b(ay) << 16);
    ((unsigned int*)(P + (size_t)node * 256))[lane] = o;
}

// ---- fused GEMM1+GEMM2 (MFMA): t2 = bf16( relu(agg@W1+b1) @ W2 ), in-place ----
__global__ __launch_bounds__(256) void k_gemm12(const float* __restrict__ W1,
                                                const float* __restrict__ b1,
                                                const float* __restrict__ W2,
                                                char* __restrict__ P) {
    __shared__ short Wl1[16384];                    // [ct8][ks4][lane64][j8]
    __shared__ short Wl2[8192];                     // [ct4][ks4][lane64][j8]
    __shared__ __align__(16) short Cl[4][16][128];
    const int tid = threadIdx.x;
    const int w = tid >> 6, lane = tid & 63;
    const int r0 = blockIdx.x * 64;

    for (int i = tid; i < 16384; i += 256) {
        int j = i & 7, l = (i >> 3) & 63, ks = (i >> 9) & 3, ct = i >> 11;
        int k = ks * 32 + ((l >> 4) << 3) + j;
        int c = ct * 16 + (l & 15);
        Wl1[i] = (short)f2b(W1[k * 128 + c]);
    }
    for (int i = tid; i < 8192; i += 256) {
        int j = i & 7, l = (i >> 3) & 63, ks = (i >> 9) & 3, ct = i >> 11;
        int k = ks * 32 + ((l >> 4) << 3) + j;
        int c = ct * 16 + (l & 15);
        Wl2[i] = (short)f2b(W2[k * 64 + c]);
    }
    __syncthreads();

    const int m = r0 + w * 16 + (lane & 15);
    const int quad = lane >> 4;
    const bool mok = (m < NN);
    bf16x8 a[4];
#pragma unroll
    for (int ks = 0; ks < 4; ++ks) {
        if (mok) a[ks] = *(const bf16x8*)(P + (size_t)m * 256 + (ks * 32 + quad * 8) * 2);
        else     a[ks] = bf16x8{0,0,0,0,0,0,0,0};
    }
#pragma unroll
    for (int ct = 0; ct < 8; ++ct) {
        f32x4 c = {0.f, 0.f, 0.f, 0.f};
#pragma unroll
        for (int ks = 0; ks < 4; ++ks) {
            bf16x8 b = *(const bf16x8*)&Wl1[((ct * 4 + ks) * 64 + lane) * 8];
            c = __builtin_amdgcn_mfma_f32_16x16x32_bf16(a[ks], b, c, 0, 0, 0);
        }
        int col = ct * 16 + (lane & 15);
        float bias = b1[col];
#pragma unroll
        for (int r = 0; r < 4; ++r)
            Cl[w][quad * 4 + r][col] = (short)f2b(fmaxf(c[r] + bias, 0.f));
    }
    __syncthreads();
    bf16x8 a2[4];
#pragma unroll
    for (int ks = 0; ks < 4; ++ks)
        a2[ks] = *(const bf16x8*)&Cl[w][lane & 15][ks * 32 + quad * 8];
    __syncthreads();
    short* Ct = &Cl[0][0][0];   // [64 rows][64 cols]
#pragma unroll
    for (int ct = 0; ct < 4; ++ct) {
        f32x4 c = {0.f, 0.f, 0.f, 0.f};
#pragma unroll
        for (int ks = 0; ks < 4; ++ks) {
            bf16x8 b = *(const bf16x8*)&Wl2[((ct * 4 + ks) * 64 + lane) * 8];
            c = __builtin_amdgcn_mfma_f32_16x16x32_bf16(a2[ks], b, c, 0, 0, 0);
        }
        int col = ct * 16 + (lane & 15);
#pragma unroll
        for (int r = 0; r < 4; ++r)
            Ct[(w * 16 + quad * 4 + r) * 64 + col] = (short)f2b(c[r]);
    }
    __syncthreads();
    for (int it = 0; it < 8; ++it) {
        int row = it * 2 + (lane >> 5), u = lane & 31;
        int node = r0 + w * 16 + row;
        if (node < NN)
            *(unsigned int*)(P + (size_t)node * 256 + u * 4) =
                ((const unsigned int*)&Ct[(w * 16 + row) * 64])[u];
    }
}

// ---- layer-2 aggregate + epilogue: out = t2*sn + sum w_e*t2[src] + b2, MLP=4 ----
__global__ __launch_bounds__(256) void k_agg2(const float* __restrict__ dinv,
                                              const int* __restrict__ row_start,
                                              const int* __restrict__ csr,
                                              const char* __restrict__ P,
                                              const float* __restrict__ b2,
                                              float* __restrict__ outp) {
    int node = blockIdx.x * 4 + (threadIdx.x >> 6);   // grid = NN/4 exactly
    int lane = threadIdx.x & 63;
    float dv = dinv[node]; float sn = dv * dv;
    float acc = b2f(*(const unsigned short*)(P + (size_t)node * 256 + lane * 2)) * sn;
    int base = row_start[node], end = row_start[node + 1];
    for (int i0 = base; i0 < end; i0 += 64) {
        int idx = i0 + lane;
        int s = (idx < end) ? csr[idx] : 0;
        float wv = (idx < end) ? dinv[s] * dv : 0.f;
        int m = min(64, end - i0);
        int j = 0;
        for (; j + 3 < m; j += 4) {
            int   s0 = __shfl(s, j),     s1 = __shfl(s, j + 1);
            int   s2 = __shfl(s, j + 2), s3 = __shfl(s, j + 3);
            float w0 = __shfl(wv, j),     w1 = __shfl(wv, j + 1);
            float w2 = __shfl(wv, j + 2), w3 = __shfl(wv, j + 3);
            float v0 = b2f(*(const unsigned short*)(P + (size_t)s0 * 256 + lane * 2));
            float v1 = b2f(*(const unsigned short*)(P + (size_t)s1 * 256 + lane * 2));
            float v2 = b2f(*(const unsigned short*)(P + (size_t)s2 * 256 + lane * 2));
            float v3 = b2f(*(const unsigned short*)(P + (size_t)s3 * 256 + lane * 2));
            acc = fmaf(v0, w0, acc);
            acc = fmaf(v1, w1, acc);
            acc = fmaf(v2, w2, acc);
            acc = fmaf(v3, w3, acc);
        }
        for (; j < m; ++j) {
            int s0 = __shfl(s, j);
            float w0 = __shfl(wv, j);
            float v0 = b2f(*(const unsigned short*)(P + (size_t)s0 * 256 + lane * 2));
            acc = fmaf(v0, w0, acc);
        }
    }
    outp[(size_t)node * 64 + lane] = acc + b2[lane];
}

extern "C" void kernel_launch(void* const* d_in, const int* in_sizes, int n_in,
                              void* d_out, int out_size, void* d_ws, size_t ws_size,
                              hipStream_t stream) {
    const float* x  = (const float*)d_in[0];
    const int*   ei = (const int*)d_in[1];
    const float* W1 = (const float*)d_in[2];
    const float* b1 = (const float*)d_in[3];
    const float* W2 = (const float*)d_in[4];
    const float* b2 = (const float*)d_in[5];
    float* out = (float*)d_out;
    const int* src = ei;
    const int* dst = ei + NE;

    char* ws = (char*)d_ws;
    unsigned short* xb        = (unsigned short*)(ws + 0);
    int*            ghist     = (int*)(ws + 25600000);
    int*            boffT     = (int*)(ws + 26400768);
    int*            tot       = (int*)(ws + 27201536);
    int*            bbase     = (int*)(ws + 27208192);
    int*            row_start = (int*)(ws + 27214848);
    float*          dinv      = (float*)(ws + 27614976);
    int*            ebuf      = (int*)(ws + 28014976);
    int*            csr       = (int*)(ws + 34414976);
    char*           P         = ws + 40814976;

    k_pre  <<<NBXB + NBH, 256, 0, stream>>>(x, xb, dst, ghist);
    k_scanB<<<(NBUCK + 255) / 256, 256, 0, stream>>>(ghist, boffT, tot);
    k_scanT<<<1, 256, 0, stream>>>(tot, bbase);
    k_place<<<NBH, 256, 0, stream>>>(src, dst, bbase, boffT, ebuf);
    k_binC <<<NBUCK, 256, 0, stream>>>(bbase, tot, ebuf, row_start, dinv, csr);

    k_agg1  <<<NN / 4, 256, 0, stream>>>(xb, dinv, row_start, csr, P);
    k_gemm12<<<NBG, 256, 0, stream>>>(W1, b1, W2, P);
    k_agg2  <<<NN / 4, 256, 0, stream>>>(dinv, row_start, csr, P, b2, out);
}